// Round 6
// baseline (457.478 us; speedup 1.0000x reference)
//
#include <hip/hip_runtime.h>
#include <math.h>

// Problem constants (reference: VOCAB=10000, HID=256, B=64, T=64)
#define VOCABN 10000
#define HIDN   256
#define GATES  1024   // 4*HID
#define BN     64
#define TN     64
#define BT     4096   // B*T
#define NCT    625    // vocab col-tiles of 16 (10000 = 625*16 exactly)

typedef unsigned int       u32;
typedef unsigned short     u16;
typedef unsigned long long u64;
typedef float v4f __attribute__((ext_vector_type(4)));
typedef short v8s __attribute__((ext_vector_type(8)));

#define SENT 0xFFFFFFFFFFFFFFFFull   // 4x bf16 -NaN: never a legal h pack

__device__ __forceinline__ float bf2f(u16 u) {
    return __uint_as_float(((u32)u) << 16);
}
__device__ __forceinline__ u16 f2bf(float f) {          // round-to-nearest-even
    u32 u = __float_as_uint(f);
    u += 0x7FFFu + ((u >> 16) & 1u);
    return (u16)(u >> 16);
}
__device__ __forceinline__ float fast_sigmoid(float x) {
    return 1.0f / (1.0f + __expf(-x));
}
__device__ __forceinline__ float fast_tanh(float x) {
    float e = __expf(-2.0f * fabsf(x));
    float t = (1.0f - e) / (1.0f + e);
    return copysignf(t, x);
}

// ---------------------------------------------------------------------------
// Generic fp32 [HIDN][ncols] -> bf16 MFMA B-fragment layout [ct][8 q][64 l][8].
// Fragment (c,q), lane l holds B[k = q*32 + (l>>4)*8 + j][n = c*16 + (l&15)],
// j=0..7, as 16 contiguous bytes -> b_frag load is a single coalesced b128.
// ---------------------------------------------------------------------------
__global__ __launch_bounds__(256) void k_wfrag(
    const float* __restrict__ src,   // [HIDN][ncols]
    u16*         __restrict__ dst,   // [nct][8][64][8]
    int ncols)
{
    __shared__ u16 lt[HIDN][16];
    const int c = blockIdx.x;
    const int t = threadIdx.x;
    const float* s = src + (size_t)t * ncols + c * 16;
    #pragma unroll
    for (int j4 = 0; j4 < 4; ++j4) {
        float4 v = *(const float4*)(s + j4 * 4);
        lt[t][j4*4+0] = f2bf(v.x);
        lt[t][j4*4+1] = f2bf(v.y);
        lt[t][j4*4+2] = f2bf(v.z);
        lt[t][j4*4+3] = f2bf(v.w);
    }
    __syncthreads();
    #pragma unroll
    for (int h = 0; h < 2; ++h) {
        int f = t + h * 256;             // frag id = q*64 + l
        int q = f >> 6, l = f & 63;
        int m = l & 15, kb = q * 32 + ((l >> 4) & 3) * 8;
        u32 w[4];
        #pragma unroll
        for (int j = 0; j < 4; ++j)
            w[j] = (u32)lt[kb + 2*j][m] | ((u32)lt[kb + 2*j + 1][m] << 16);
        *(uint4*)(dst + (((size_t)c * 8 + q) * 64 + l) * 8) =
            make_uint4(w[0], w[1], w[2], w[3]);
    }
}

// ---------------------------------------------------------------------------
// Kernel 1 (MFMA): gates_x = E[idx] @ W_x + b_lstm -> bf16. 256 blocks.
// ---------------------------------------------------------------------------
__global__ __launch_bounds__(256) void k_xgates(
    const int*   __restrict__ idx,   // [BT]
    const float* __restrict__ E,     // [VOCAB][HIDN]
    const u16*   __restrict__ Wxf,   // [64][8][64][8]
    const float* __restrict__ bl,    // [GATES]
    u16*         __restrict__ gxb)   // [BT][GATES] bf16
{
    const int r0   = blockIdx.x * 16;
    const int tid  = threadIdx.x;
    const int w    = tid >> 6, lane = tid & 63;
    const int m    = lane & 15, quad = lane >> 4;

    v8s a[8];
    {
        const float* e = E + (size_t)idx[r0 + m] * HIDN + quad * 8;
        #pragma unroll
        for (int q = 0; q < 8; ++q) {
            float4 x0 = *(const float4*)(e + q * 32);
            float4 x1 = *(const float4*)(e + q * 32 + 4);
            uint4 t4 = make_uint4(
                (u32)f2bf(x0.x) | ((u32)f2bf(x0.y) << 16),
                (u32)f2bf(x0.z) | ((u32)f2bf(x0.w) << 16),
                (u32)f2bf(x1.x) | ((u32)f2bf(x1.y) << 16),
                (u32)f2bf(x1.z) | ((u32)f2bf(x1.w) << 16));
            a[q] = *(v8s*)&t4;
        }
    }

    for (int c = w; c < GATES / 16; c += 4) {
        v4f acc = {0.f, 0.f, 0.f, 0.f};
        #pragma unroll
        for (int q = 0; q < 8; ++q) {
            v8s b = *(const v8s*)(Wxf + (((size_t)c * 8 + q) * 64 + lane) * 8);
            acc = __builtin_amdgcn_mfma_f32_16x16x32_bf16(a[q], b, acc, 0, 0, 0);
        }
        const int col = c * 16 + m;
        const float bv = bl[col];
        #pragma unroll
        for (int r = 0; r < 4; ++r)   // D: col=lane&15, row=quad*4+r (m89/m91)
            gxb[(size_t)(r0 + quad * 4 + r) * GATES + col] = f2bf(acc[r] + bv);
    }
}

// ---------------------------------------------------------------------------
// Kernel 2 (persistent MFMA LSTM, barrier-free): 32 blocks = 4 row-groups
// (16 rows) x 8 unit-slices (32 units). W_h slice (64 KB) LDS-resident.
// Cross-block h-exchange: per-step LLC buffers Hx[t] pre-filled with the
// 0xFFFF sentinel; producers publish via relaxed agent u64 stores, consumers
// POLL THE DATA WORDS directly (no counter, no fences, no buffer_inv).
// Producers never wait; the h(t-1)->h(t) chain is the only serialization.
// ---------------------------------------------------------------------------
__global__ __launch_bounds__(256) void k_plstm(
    const u16*   __restrict__ Whf,   // [64 ct][8][64][8] h-part frags
    const u16*   __restrict__ gxb,   // [BT][GATES] bf16
    u16*                      Hx,    // [63][BN][HIDN] bf16, sentinel-filled
    u16*         __restrict__ Hb)    // [BT][HIDN] bf16 output
{
    __shared__ uint4 Wl4[8 * 512];       // 64 KB: 8 tiles in B-frag layout
    __shared__ float gl[4][16][33];      // gate exchange (+1 pad)

    const int tid  = threadIdx.x;
    const int rg   = blockIdx.x >> 3;    // row group: batch rows rg*16..+15
    const int ns   = blockIdx.x & 7;     // unit slice: units ns*32..+31
    const int u0   = ns * 32;
    const int w    = tid >> 6;           // wave = gate type (i,j,f,o)
    const int lane = tid & 63;
    const int m    = lane & 15, kq = lane >> 4;

    // --- load W_h slice: tiles ct = g*16 + ns*2 + ut (g=0..3, ut=0..1) ---
    {
        const uint4* src = (const uint4*)Whf;
        #pragma unroll
        for (int i = 0; i < 16; ++i) {
            int e  = tid + i * 256;          // [0, 4096)
            int tl = e >> 9, off = e & 511;  // local tile, offset in tile
            int ct = (tl >> 1) * 16 + ns * 2 + (tl & 1);
            Wl4[e] = src[(size_t)ct * 512 + off];
        }
    }
    for (int e = tid; e < 4 * 16 * 33; e += 256) ((float*)gl)[e] = 0.0f;
    __syncthreads();

    const u16* Wl = (const u16*)Wl4;

    // thread identity for cell phase: (row r, units u0+u and u0+16+u)
    const int r = tid >> 4, u = tid & 15;
    const int b = rg * 16 + r;                       // batch row
    const u16* gxp = gxb + (size_t)b * TN * GATES + u0 + u;
    u16* hbp  = Hb + (size_t)b * TN * HIDN + u0 + u;
    const size_t hxw = (size_t)b * HIDN + u0 + u;    // publish elem offset
    // consumer a-frag base (u64 units): row picks m, k picks kq
    const size_t arow64 = (size_t)(rg * 16 + m) * (HIDN / 4) + kq * 2;

    float cst0 = 0.0f, cst1 = 0.0f;
    float gr[8], gn[8];
    #pragma unroll
    for (int g = 0; g < 4; ++g) {
        gr[g]     = bf2f(gxp[g * 256]);
        gr[g + 4] = bf2f(gxp[g * 256 + 16]);
    }

    for (int t = 0; t < TN; ++t) {
        // prefetch next step's x-gates (hide latency behind this step)
        if (t + 1 < TN) {
            const u16* p = gxp + (size_t)(t + 1) * GATES;
            #pragma unroll
            for (int g = 0; g < 4; ++g) {
                gn[g]     = bf2f(p[g * 256]);
                gn[g + 4] = bf2f(p[g * 256 + 16]);
            }
        }

        if (t > 0) {
            // ---- poll h(t-1) data words at LLC until all non-sentinel ----
            const u64* hb64 = (const u64*)(Hx) + (size_t)(t - 1) * (BN * HIDN / 4)
                              + arow64;
            u64 d0[8], d1[8];
            #pragma unroll
            for (int q = 0; q < 8; ++q) { d0[q] = SENT; d1[q] = SENT; }
            bool ok = false;
            while (!ok) {
                u64 t0[8], t1[8];
                #pragma unroll
                for (int q = 0; q < 8; ++q) {
                    t0[q] = __hip_atomic_load(hb64 + q * 8,     __ATOMIC_RELAXED,
                                              __HIP_MEMORY_SCOPE_AGENT);
                    t1[q] = __hip_atomic_load(hb64 + q * 8 + 1, __ATOMIC_RELAXED,
                                              __HIP_MEMORY_SCOPE_AGENT);
                }
                ok = true;
                #pragma unroll
                for (int q = 0; q < 8; ++q) {
                    d0[q] = t0[q]; d1[q] = t1[q];
                    if (t0[q] == SENT || t1[q] == SENT) ok = false;
                }
            }
            // ---- 16 MFMA: 2 unit-tiles, a-frags shared across tiles ----
            v4f acc0 = {0.f,0.f,0.f,0.f}, acc1 = {0.f,0.f,0.f,0.f};
            #pragma unroll
            for (int q = 0; q < 8; ++q) {
                union { u64 d[2]; v8s v; } av;
                av.d[0] = d0[q]; av.d[1] = d1[q];
                v8s bf0 = *(const v8s*)(Wl + (((w * 2 + 0) * 8 + q) * 64 + lane) * 8);
                v8s bf1 = *(const v8s*)(Wl + (((w * 2 + 1) * 8 + q) * 64 + lane) * 8);
                acc0 = __builtin_amdgcn_mfma_f32_16x16x32_bf16(av.v, bf0, acc0, 0, 0, 0);
                acc1 = __builtin_amdgcn_mfma_f32_16x16x32_bf16(av.v, bf1, acc1, 0, 0, 0);
            }
            #pragma unroll
            for (int rr = 0; rr < 4; ++rr) {  // row = kq*4+rr, unit col = m
                gl[w][kq * 4 + rr][m]      = acc0[rr];
                gl[w][kq * 4 + rr][16 + m] = acc1[rr];
            }
        }
        __syncthreads();

        {   // cell update for (r, u) and (r, u+16); c states in registers
            float ai0 = gl[0][r][u]      + gr[0];
            float aj0 = gl[1][r][u]      + gr[1];
            float af0 = gl[2][r][u]      + gr[2];
            float ao0 = gl[3][r][u]      + gr[3];
            float ai1 = gl[0][r][u + 16] + gr[4];
            float aj1 = gl[1][r][u + 16] + gr[5];
            float af1 = gl[2][r][u + 16] + gr[6];
            float ao1 = gl[3][r][u + 16] + gr[7];

            float ig0 = fast_sigmoid(ai0), fg0 = fast_sigmoid(af0 + 1.0f);
            float og0 = fast_sigmoid(ao0), jt0 = fast_tanh(aj0);
            cst0 = fg0 * cst0 + ig0 * jt0;
            float hn0 = og0 * fast_tanh(cst0);
            float ig1 = fast_sigmoid(ai1), fg1 = fast_sigmoid(af1 + 1.0f);
            float og1 = fast_sigmoid(ao1), jt1 = fast_tanh(aj1);
            cst1 = fg1 * cst1 + ig1 * jt1;
            float hn1 = og1 * fast_tanh(cst1);

            u32 h0 = f2bf(hn0), h1 = f2bf(hn1);

            if (t + 1 < TN) {
                // pack 4 consecutive units into u64, publish to LLC ASAP
                u32 a1 = __shfl_down(h0, 1), a2 = __shfl_down(h0, 2), a3 = __shfl_down(h0, 3);
                u32 b1 = __shfl_down(h1, 1), b2 = __shfl_down(h1, 2), b3 = __shfl_down(h1, 3);
                if ((tid & 3) == 0) {
                    u64* dst = (u64*)(Hx + (size_t)t * (BN * HIDN) + hxw);
                    u64 pk0 = (u64)(h0 | (a1 << 16)) | ((u64)(a2 | (a3 << 16)) << 32);
                    u64 pk1 = (u64)(h1 | (b1 << 16)) | ((u64)(b2 | (b3 << 16)) << 32);
                    __hip_atomic_store(dst,     pk0, __ATOMIC_RELAXED,
                                       __HIP_MEMORY_SCOPE_AGENT);
                    __hip_atomic_store(dst + 4, pk1, __ATOMIC_RELAXED,
                                       __HIP_MEMORY_SCOPE_AGENT);
                }
            }
            hbp[(size_t)t * HIDN]      = (u16)h0;
            hbp[(size_t)t * HIDN + 16] = (u16)h1;
        }

        if (t + 1 < TN) __syncthreads();   // gl reads done before next writes
        #pragma unroll
        for (int g = 0; g < 8; ++g) gr[g] = gn[g];
    }
}

// ---------------------------------------------------------------------------
// Kernel 3 (MFMA): sum-of-exp over vocab (no running max: |logit| small, exp
// never overflows fp32). 256 blocks = 128 row-groups x 2 vocab halves.
// ---------------------------------------------------------------------------
__global__ __launch_bounds__(256) void k_dense(
    const u16*   __restrict__ Hb,    // [BT][HIDN] bf16
    const u16*   __restrict__ Wf,    // [625][8][64][8]
    const float* __restrict__ bd,    // [VOCAB]
    float*       __restrict__ S)     // [2][BT] partial sumexp
{
    __shared__ float Sl[32];
    const int rg  = blockIdx.x >> 1, hv = blockIdx.x & 1;
    const int r0  = rg * 32;
    const int tid = threadIdx.x;
    const int w   = tid >> 6, lane = tid & 63;
    const int m   = lane & 15, quad = lane >> 4;

    if (tid < 32) Sl[tid] = 0.0f;

    v8s a[2][8];
    #pragma unroll
    for (int rt = 0; rt < 2; ++rt) {
        const u16* hrow = Hb + (size_t)(r0 + rt * 16 + m) * HIDN + quad * 8;
        #pragma unroll
        for (int q = 0; q < 8; ++q)
            a[rt][q] = *(const v8s*)(hrow + q * 32);
    }
    __syncthreads();

    float s[2][4] = {{0.f,0.f,0.f,0.f},{0.f,0.f,0.f,0.f}};
    const int cbeg = hv ? 313 : 0;
    const int cend = hv ? NCT : 313;
    for (int c = cbeg + w; c < cend; c += 4) {
        v4f acc0 = {0.f,0.f,0.f,0.f};
        v4f acc1 = {0.f,0.f,0.f,0.f};
        #pragma unroll
        for (int q = 0; q < 8; ++q) {
            v8s bq = *(const v8s*)(Wf + (((size_t)c * 8 + q) * 64 + lane) * 8);
            acc0 = __builtin_amdgcn_mfma_f32_16x16x32_bf16(a[0][q], bq, acc0, 0, 0, 0);
            acc1 = __builtin_amdgcn_mfma_f32_16x16x32_bf16(a[1][q], bq, acc1, 0, 0, 0);
        }
        float bv = bd[c * 16 + m];
        #pragma unroll
        for (int r = 0; r < 4; ++r) {
            s[0][r] += __expf(acc0[r] + bv);
            s[1][r] += __expf(acc1[r] + bv);
        }
    }

    #pragma unroll
    for (int rt = 0; rt < 2; ++rt)
        #pragma unroll
        for (int r = 0; r < 4; ++r)
            atomicAdd(&Sl[rt * 16 + quad * 4 + r], s[rt][r]);
    __syncthreads();
    if (tid < 32) S[(size_t)hv * BT + r0 + tid] = Sl[tid];
}

// ---------------------------------------------------------------------------
// Kernel 4: target logit per row (direct dot from bf16 frags). 32 thr/row.
// ---------------------------------------------------------------------------
__global__ __launch_bounds__(256) void k_target(
    const u16*   __restrict__ Hb,
    const u16*   __restrict__ Wf,
    const float* __restrict__ bd,
    const int*   __restrict__ tgt,
    float*       __restrict__ tl)    // [BT]
{
    const int tid = threadIdx.x;
    const int row = blockIdx.x * 8 + (tid >> 5);
    const int t   = tid & 31;
    const int q   = t >> 2, lq = t & 3;
    const int v   = tgt[row];
    const int c   = v >> 4, vm = v & 15;
    const int kb  = q * 32 + lq * 8;

    v8s h  = *(const v8s*)(Hb + (size_t)row * HIDN + kb);
    v8s wv = *(const v8s*)(Wf + (((size_t)c * 8 + q) * 64 + lq * 16 + vm) * 8);
    float acc = 0.0f;
    #pragma unroll
    for (int j = 0; j < 8; ++j)
        acc = fmaf(bf2f((u16)h[j]), bf2f((u16)wv[j]), acc);
    #pragma unroll
    for (int off = 16; off >= 1; off >>= 1)
        acc += __shfl_down(acc, off, 32);
    if (t == 0) tl[row] = acc + bd[v];
}

// ---------------------------------------------------------------------------
// Kernel 5: ppl = exp(log(sumexp) - target_logit)
// ---------------------------------------------------------------------------
__global__ __launch_bounds__(256) void k_final(
    const float* __restrict__ S,     // [2][BT]
    const float* __restrict__ tl,    // [BT]
    float*       __restrict__ out)   // [BT]
{
    int i = blockIdx.x * 256 + threadIdx.x;
    out[i] = __expf(__logf(S[i] + S[BT + i]) - tl[i]);
}

// ---------------------------------------------------------------------------
extern "C" void kernel_launch(void* const* d_in, const int* in_sizes, int n_in,
                              void* d_out, int out_size, void* d_ws, size_t ws_size,
                              hipStream_t stream) {
    const int*   input   = (const int*)  d_in[0];   // [B,T]
    const int*   targets = (const int*)  d_in[1];   // [B,T]
    const float* E       = (const float*)d_in[2];   // [VOCAB,HID]
    const float* W_lstm  = (const float*)d_in[3];   // [2H,4H]
    const float* b_lstm  = (const float*)d_in[4];   // [4H]
    const float* W_dense = (const float*)d_in[5];   // [HID,VOCAB]
    const float* b_dense = (const float*)d_in[6];   // [VOCAB]
    float* out = (float*)d_out;                     // [B,T] perplexity

    // Workspace (~13.05 MB, well under the 20 MB proven in earlier rounds):
    //  [0,8M):        gxb bf16 [BT][GATES]; Wf (5.12 MB) reuses this region
    //                 after k_plstm has consumed gxb — stream-ordered.
    //  [8M,10M):      Hb bf16 [BT][HIDN]
    //  [10M,+512K):   Whf (h-part frags)
    //  [10.5M,+512K): Wxf (x-part frags)
    //  [11M,13M):     Hx bf16 [63][BN][HIDN] sentinel-initialized exchange
    //  [13M,+32K):    S fp32 [2][BT]
    //  [13M+32K,+16K):tl fp32 [BT]
    char* ws = (char*)d_ws;
    u16*   gxb = (u16*)ws;
    u16*   Wf  = (u16*)ws;
    u16*   Hb  = (u16*)(ws + ((size_t)8  << 20));
    u16*   Whf = (u16*)(ws + ((size_t)10 << 20));
    u16*   Wxf = (u16*)(ws + ((size_t)10 << 20) + ((size_t)512 << 10));
    u16*   Hx  = (u16*)(ws + ((size_t)11 << 20));
    float* S   = (float*)(ws + ((size_t)13 << 20));
    float* tl  = (float*)(ws + ((size_t)13 << 20) + ((size_t)32 << 10));

    hipMemsetAsync(Hx, 0xFF, (size_t)2 << 20, stream);   // sentinel fill
    k_wfrag <<<64,      256, 0, stream>>>(W_lstm,                      Wxf, GATES);
    k_wfrag <<<64,      256, 0, stream>>>(W_lstm + (size_t)HIDN*GATES, Whf, GATES);
    k_xgates<<<BT / 16, 256, 0, stream>>>(input, E, Wxf, b_lstm, gxb);
    k_plstm <<<32,      256, 0, stream>>>(Whf, gxb, Hx, Hb);
    k_wfrag <<<NCT,     256, 0, stream>>>(W_dense, Wf, VOCABN);   // reuses gxb
    k_dense <<<256,     256, 0, stream>>>(Hb, Wf, b_dense, S);
    k_target<<<BT / 8,  256, 0, stream>>>(Hb, Wf, b_dense, targets, tl);
    k_final <<<BT / 256,256, 0, stream>>>(S, tl, out);
}